// Round 8
// baseline (135.753 us; speedup 1.0000x reference)
//
#include <hip/hip_runtime.h>
#include <stdint.h>

#define B_ 2
#define T_ 2048
#define C_ 1024
#define H_ 16
#define D_ 64
// SCALE * log2(e): softmax computed in exp2 domain; folded into Q at rope time
#define SCALE_L2E 0.1803368801111244f

typedef unsigned short ushort_t;
typedef __attribute__((ext_vector_type(8))) __bf16 bf16x8;
typedef __attribute__((ext_vector_type(4))) float f32x4;
typedef __attribute__((ext_vector_type(4))) unsigned short ushort4_t;

__device__ __forceinline__ float bf2f(ushort_t u) {
    union { unsigned int u; float f; } v; v.u = ((unsigned int)u) << 16; return v.f;
}
// native f32->bf16 (compiler emits v_cvt_pk_bf16_f32, RNE)
__device__ __forceinline__ ushort_t f2bf(float f) {
    union { __bf16 h; ushort_t u; } v; v.h = (__bf16)f; return v.u;
}

__device__ __forceinline__ void gl16(const void* g, void* l) {
    __builtin_amdgcn_global_load_lds(
        (const __attribute__((address_space(1))) void*)g,
        (__attribute__((address_space(3))) void*)l, 16, 0, 0);
}

__device__ __forceinline__ f32x4 mfma16(bf16x8 a, bf16x8 b, f32x4 c) {
    return __builtin_amdgcn_mfma_f32_16x16x32_bf16(a, b, c, 0, 0, 0);
}

// ---------------- fused fp32 -> bf16 convert (3 tensors) ----------------
__global__ __launch_bounds__(256) void cvt3_kernel(const float* __restrict__ a, ushort_t* __restrict__ oa, int na,
                                                   const float* __restrict__ b, ushort_t* __restrict__ ob, int nb,
                                                   const float* __restrict__ c, ushort_t* __restrict__ oc, int nc) {
    int total4 = (na + nb + nc) >> 2;
    int stride = gridDim.x * blockDim.x;
    for (int i = blockIdx.x * blockDim.x + threadIdx.x; i < total4; i += stride) {
        int e = i << 2;
        const float* src; ushort_t* dst; int off;
        if (e < na) { src = a; dst = oa; off = e; }
        else if (e < na + nb) { src = b; dst = ob; off = e - na; }
        else { src = c; dst = oc; off = e - na - nb; }
        float4 v = *(const float4*)(src + off);
        ushort4_t o;
        o.x = f2bf(v.x); o.y = f2bf(v.y); o.z = f2bf(v.z); o.w = f2bf(v.w);
        *(ushort4_t*)(dst + off) = o;
    }
}

// ---------------- GEMM (proj): C[M,N] = A[M,K]*B[N,K]^T + bias, fp32 out ----------------
__global__ __launch_bounds__(256) void gemm_proj(const ushort_t* __restrict__ A,
                                                 const ushort_t* __restrict__ Bw,
                                                 const float* __restrict__ bias,
                                                 float* __restrict__ outf,
                                                 int M, int N, int K, int nxt) {
    int q = gridDim.x >> 3;
    int nid = (blockIdx.x & 7) * q + (blockIdx.x >> 3);
    int bx = nid % nxt, by = nid / nxt;

    __shared__ ushort_t sm[16384];   // 2 bufs x (As 4096 + Bs 4096)
    int tid = threadIdx.x, w = tid >> 6, lane = tid & 63;
    int lr = lane >> 4, lc = lane & 15;
    int wr = w >> 1, wc = w & 1;
    int row0 = by * 128, col0 = bx * 128;

    f32x4 acc[4][4];
#pragma unroll
    for (int mf = 0; mf < 4; ++mf)
#pragma unroll
        for (int nf = 0; nf < 4; ++nf) acc[mf][nf] = (f32x4){0.f, 0.f, 0.f, 0.f};

    auto stageg = [&](int buf, int k0) {
#pragma unroll
        for (int j = 0; j < 2; ++j) {
            int idx = j * 256 + tid;
            int r = idx >> 2, c = (idx & 3) * 8;
            gl16(A + (size_t)(row0 + r) * K + k0 + c, &sm[buf * 8192 + idx * 8]);
            gl16(Bw + (size_t)(col0 + r) * K + k0 + c, &sm[buf * 8192 + 4096 + idx * 8]);
        }
    };

    stageg(0, 0);
    asm volatile("s_waitcnt vmcnt(0)" ::: "memory");
    __builtin_amdgcn_s_barrier();

    for (int k0 = 0; k0 < K; k0 += 32) {
        int cur = (k0 >> 5) & 1;
        if (k0 + 32 < K) stageg(cur ^ 1, k0 + 32);
        const ushort_t* As = &sm[cur * 8192];
        const ushort_t* Bs = &sm[cur * 8192 + 4096];
        bf16x8 af[4], bfr[4];
#pragma unroll
        for (int mf = 0; mf < 4; ++mf)
            af[mf] = *(const bf16x8*)&As[(wr * 64 + mf * 16 + lc) * 32 + 8 * lr];
#pragma unroll
        for (int nf = 0; nf < 4; ++nf)
            bfr[nf] = *(const bf16x8*)&Bs[(wc * 64 + nf * 16 + lc) * 32 + 8 * lr];
        __builtin_amdgcn_s_setprio(1);
#pragma unroll
        for (int mf = 0; mf < 4; ++mf)
#pragma unroll
            for (int nf = 0; nf < 4; ++nf)
                acc[mf][nf] = mfma16(af[mf], bfr[nf], acc[mf][nf]);
        __builtin_amdgcn_s_setprio(0);
        asm volatile("s_waitcnt vmcnt(0)" ::: "memory");
        __builtin_amdgcn_s_barrier();
    }
#pragma unroll
    for (int mf = 0; mf < 4; ++mf)
#pragma unroll
        for (int nf = 0; nf < 4; ++nf) {
            int col = col0 + wc * 64 + nf * 16 + lc;
            float bv = bias[col];
#pragma unroll
            for (int r = 0; r < 4; ++r) {
                int row = row0 + wr * 64 + mf * 16 + 4 * lr + r;
                outf[(size_t)row * N + col] = acc[mf][nf][r] + bv;
            }
        }
}

// ---------------- GEMM1 fused: QKV = X*Wqkv^T + b, + RoPE + scatter ----------------
__global__ __launch_bounds__(256) void gemm_qkv_rope(const ushort_t* __restrict__ A,
                                                     const ushort_t* __restrict__ Bw,
                                                     const float* __restrict__ bias,
                                                     const float* __restrict__ cosT,
                                                     const float* __restrict__ sinT,
                                                     ushort_t* __restrict__ Qr,
                                                     ushort_t* __restrict__ Kr,
                                                     ushort_t* __restrict__ Vt) {
    const int K = 1024;
    int nid = (blockIdx.x & 7) * 96 + (blockIdx.x >> 3);
    int bx = nid % 24, by = nid / 24;

    __shared__ ushort_t sm[16384];   // dbuf staging; aliased as V-transpose tile after K-loop
    int tid = threadIdx.x, w = tid >> 6, lane = tid & 63;
    int lr = lane >> 4, lc = lane & 15;
    int wr = w >> 1, wc = w & 1;
    int row0 = by * 128, col0 = bx * 128;

    f32x4 acc[4][4];
#pragma unroll
    for (int mf = 0; mf < 4; ++mf)
#pragma unroll
        for (int nf = 0; nf < 4; ++nf) acc[mf][nf] = (f32x4){0.f, 0.f, 0.f, 0.f};

    auto stageg = [&](int buf, int k0) {
#pragma unroll
        for (int j = 0; j < 2; ++j) {
            int idx = j * 256 + tid;
            int r = idx >> 2, c = (idx & 3) * 8;
            gl16(A + (size_t)(row0 + r) * K + k0 + c, &sm[buf * 8192 + idx * 8]);
            gl16(Bw + (size_t)(col0 + r) * K + k0 + c, &sm[buf * 8192 + 4096 + idx * 8]);
        }
    };

    stageg(0, 0);
    asm volatile("s_waitcnt vmcnt(0)" ::: "memory");
    __builtin_amdgcn_s_barrier();

    for (int k0 = 0; k0 < K; k0 += 32) {
        int cur = (k0 >> 5) & 1;
        if (k0 + 32 < K) stageg(cur ^ 1, k0 + 32);
        const ushort_t* As = &sm[cur * 8192];
        const ushort_t* Bs = &sm[cur * 8192 + 4096];
        bf16x8 af[4], bfr[4];
#pragma unroll
        for (int mf = 0; mf < 4; ++mf)
            af[mf] = *(const bf16x8*)&As[(wr * 64 + mf * 16 + lc) * 32 + 8 * lr];
#pragma unroll
        for (int nf = 0; nf < 4; ++nf)
            bfr[nf] = *(const bf16x8*)&Bs[(wc * 64 + nf * 16 + lc) * 32 + 8 * lr];
        __builtin_amdgcn_s_setprio(1);
#pragma unroll
        for (int mf = 0; mf < 4; ++mf)
#pragma unroll
            for (int nf = 0; nf < 4; ++nf)
                acc[mf][nf] = mfma16(af[mf], bfr[nf], acc[mf][nf]);
        __builtin_amdgcn_s_setprio(0);
        asm volatile("s_waitcnt vmcnt(0)" ::: "memory");
        __builtin_amdgcn_s_barrier();
    }

    if (bx < 16) {
        // ---- Q / K epilogue with RoPE ----
        const int typ = bx >> 3;                 // 0 = Q, 1 = K
        ushort_t* dstb = typ ? Kr : Qr;
#pragma unroll
        for (int nf = 0; nf < 4; ++nf) {
            int fullc = col0 + wc * 64 + nf * 16 + lc;
            int gc = fullc & 1023;
            int h = gc >> 6;
            int d2 = (gc & 63) >> 1;
            int odd = gc & 1;
            float bv = bias[fullc];
#pragma unroll
            for (int mf = 0; mf < 4; ++mf)
#pragma unroll
                for (int r = 0; r < 4; ++r) {
                    int row = row0 + wr * 64 + mf * 16 + 4 * lr + r;
                    int bb = row >> 11, t = row & 2047;
                    float v = acc[mf][nf][r] + bv;
                    float pv = __shfl_xor(v, 1, 64);   // partner column (2d2 <-> 2d2+1)
                    float cth = cosT[t * 32 + d2], sth = sinT[t * 32 + d2];
                    float o = odd ? (pv * sth + v * cth) : (v * cth - pv * sth);
                    if (typ == 0) o *= SCALE_L2E;
                    int od = odd ? (d2 + 32) : d2;
                    dstb[((size_t)(bb * H_ + h) * T_ + t) * D_ + od] = f2bf(o);
                }
        }
    } else {
        // ---- V epilogue: transpose 128t x 64c half-tiles through LDS ----
        int bb = row0 >> 11;
        int tb = row0 & 2047;
#pragma unroll 1
        for (int half = 0; half < 2; ++half) {
            __syncthreads();
            if (wc == half) {
#pragma unroll
                for (int nf = 0; nf < 4; ++nf) {
                    int fullc = col0 + wc * 64 + nf * 16 + lc;
                    float bv = bias[fullc];
                    int c = nf * 16 + lc;     // 0..63 within this head
#pragma unroll
                    for (int mf = 0; mf < 4; ++mf)
#pragma unroll
                        for (int r = 0; r < 4; ++r) {
                            int tl = wr * 64 + mf * 16 + 4 * lr + r;
                            sm[c * 136 + tl] = f2bf(acc[mf][nf][r] + bv);
                        }
                }
            }
            __syncthreads();
            int h = ((bx - 16) << 1) + half;
#pragma unroll
            for (int it = 0; it < 8; ++it) {
                int idx = it * 256 + tid;
                int c = idx >> 5, j = idx & 31;
                ushort4_t vv = *(const ushort4_t*)&sm[c * 136 + 4 * j];
                *(ushort4_t*)&Vt[((size_t)(bb * H_ + h) * D_ + c) * T_ + tb + 4 * j] = vv;
            }
        }
    }
}

// ---------------- causal flash attention: QBLK=128 (2 sub-tiles/wave) ----------------
// grid 512 = 32 bh x 16 super-tiles (128 q-rows). Same-CU pair {id, id+256}:
// same bh (K/V L2-hot) and s pair {s, 15-s} => exactly 34 kv-iters per CU.
// Per kv-tile: K/V fragments loaded ONCE feed both sub-tiles (LDS reads/work halved).
// Swapped mfma(K,Q): scalar m per lane; l via ones-MFMA; defer-max THR=8.
__global__ __launch_bounds__(256) void attn_kernel(const ushort_t* __restrict__ Qr,
                                                   const ushort_t* __restrict__ Kr,
                                                   const ushort_t* __restrict__ Vt,
                                                   ushort_t* __restrict__ attnb) {
    int id = blockIdx.x;
    int lo = id & 255, hi = id >> 8;
    int x = lo & 7, cc = lo >> 3;
    int bh = x + 8 * (cc & 3);          // bh % 8 == XCD
    int s = hi ? (15 - (cc >> 2)) : (cc >> 2);
    int b = bh >> 4, h = bh & 15;

    const ushort_t* Qp = Qr + (size_t)bh * T_ * D_;
    const ushort_t* Kp = Kr + (size_t)bh * T_ * D_;
    const ushort_t* Vp = Vt + (size_t)bh * D_ * T_;
    int tid = threadIdx.x, w = tid >> 6, lane = tid & 63;
    int lr = lane >> 4, lc = lane & 15;

    __shared__ ushort_t Ks[2][64 * 64];
    __shared__ ushort_t Vs[2][64 * 64];
    __shared__ ushort_t Ps[4][2][16 * 64];

    bf16x8 ones;
#pragma unroll
    for (int i = 0; i < 8; ++i) ones[i] = (__bf16)1.0f;

    auto stage = [&](int buf, int kt) {
        int t0 = kt * 64;
#pragma unroll
        for (int j = 0; j < 2; ++j) {
            int idx = j * 256 + tid;
            int row = idx >> 3, ch = idx & 7;
            int sch = ch ^ (row & 7);
            gl16(Kp + (size_t)(t0 + row) * D_ + sch * 8, &Ks[buf][idx * 8]);
            gl16(Vp + (size_t)row * T_ + t0 + sch * 8, &Vs[buf][idx * 8]);
        }
    };

    int q0 = s * 128 + w * 16;               // sub0 base; sub1 = +64
    bf16x8 qa0 = *(const bf16x8*)(Qp + (size_t)(q0 + lc) * D_ + 8 * lr);
    bf16x8 qa1 = *(const bf16x8*)(Qp + (size_t)(q0 + lc) * D_ + 32 + 8 * lr);
    bf16x8 qb0 = *(const bf16x8*)(Qp + (size_t)(q0 + 64 + lc) * D_ + 8 * lr);
    bf16x8 qb1 = *(const bf16x8*)(Qp + (size_t)(q0 + 64 + lc) * D_ + 32 + 8 * lr);

    float m0 = 0.f, m1 = 0.f;               // scalar running max per lane (q = lc)
    f32x4 acc0[4], acc1[4], l0, l1;
#pragma unroll
    for (int f = 0; f < 4; ++f) {
        acc0[f] = (f32x4){0.f, 0.f, 0.f, 0.f};
        acc1[f] = (f32x4){0.f, 0.f, 0.f, 0.f};
    }
    l0 = (f32x4){0.f, 0.f, 0.f, 0.f};
    l1 = (f32x4){0.f, 0.f, 0.f, 0.f};

    int nkt = 2 * s + 2;

    stage(0, 0);
    asm volatile("s_waitcnt vmcnt(0)" ::: "memory");
    __builtin_amdgcn_s_barrier();

    for (int kt = 0; kt < nkt; ++kt) {
        int cur = kt & 1;
        if (kt + 1 < nkt) stage(cur ^ 1, kt + 1);
        bool has0 = (kt <= 2 * s);
        bool d0t = (kt == 2 * s);
        bool d1t = (kt == nkt - 1);

        // S^T - m: rows = k (16f+4lr+r), cols = q (lc); K frag read once, used twice
        f32x4 sv0[4], sv1[4];
        __builtin_amdgcn_s_setprio(1);
#pragma unroll
        for (int f = 0; f < 4; ++f) {
            sv0[f] = (f32x4){-m0, -m0, -m0, -m0};
            sv1[f] = (f32x4){-m1, -m1, -m1, -m1};
            int row = 16 * f + lc;
#pragma unroll
            for (int kk = 0; kk < 2; ++kk) {
                bf16x8 kf = *(const bf16x8*)&Ks[cur][row * 64 + (((lr + 4 * kk) ^ (row & 7)) * 8)];
                if (has0) sv0[f] = mfma16(kf, kk ? qa1 : qa0, sv0[f]);
                sv1[f] = mfma16(kf, kk ? qb1 : qb0, sv1[f]);
            }
        }
        __builtin_amdgcn_s_setprio(0);

        // causal mask on diagonal tiles (local condition identical for both subs)
        if (d0t) {
#pragma unroll
            for (int f = 0; f < 4; ++f)
#pragma unroll
                for (int r = 0; r < 4; ++r)
                    if (16 * f + 4 * lr + r > w * 16 + lc) sv0[f][r] = -1e30f;
        }
        if (d1t) {
#pragma unroll
            for (int f = 0; f < 4; ++f)
#pragma unroll
                for (int r = 0; r < 4; ++r)
                    if (16 * f + 4 * lr + r > w * 16 + lc) sv1[f][r] = -1e30f;
        }

        float lm0 = -1e30f, lm1 = -1e30f;
        if (has0) {
#pragma unroll
            for (int f = 0; f < 4; ++f)
#pragma unroll
                for (int r = 0; r < 4; ++r) lm0 = fmaxf(lm0, sv0[f][r]);
        }
#pragma unroll
        for (int f = 0; f < 4; ++f)
#pragma unroll
            for (int r = 0; r < 4; ++r) lm1 = fmaxf(lm1, sv1[f][r]);

        // defer-max: rare path only when some row grew past m_old + 8
        if (!__all(fmaxf(lm0, lm1) <= 8.0f)) {
            // sub0
            {
                float tm = fmaxf(lm0, __shfl_xor(lm0, 16, 64));
                tm = fmaxf(tm, __shfl_xor(tm, 32, 64));
                float d = fmaxf(tm, 0.f);
                m0 += d;
                float al = exp2f(-d);
                float ar[4];
#pragma unroll
                for (int r = 0; r < 4; ++r) ar[r] = __shfl(al, 4 * lr + r, 64);
#pragma unroll
                for (int r = 0; r < 4; ++r) {
                    l0[r] *= ar[r];
#pragma unroll
                    for (int f = 0; f < 4; ++f) acc0[f][r] *= ar[r];
                }
#pragma unroll
                for (int f = 0; f < 4; ++f)
#pragma unroll
                    for (int r = 0; r < 4; ++r) sv0[f][r] -= d;
            }
            // sub1
            {
                float tm = fmaxf(lm1, __shfl_xor(lm1, 16, 64));
                tm = fmaxf(tm, __shfl_xor(tm, 32, 64));
                float d = fmaxf(tm, 0.f);
                m1 += d;
                float al = exp2f(-d);
                float ar[4];
#pragma unroll
                for (int r = 0; r < 4; ++r) ar[r] = __shfl(al, 4 * lr + r, 64);
#pragma unroll
                for (int r = 0; r < 4; ++r) {
                    l1[r] *= ar[r];
#pragma unroll
                    for (int f = 0; f < 4; ++f) acc1[f][r] *= ar[r];
                }
#pragma unroll
                for (int f = 0; f < 4; ++f)
#pragma unroll
                    for (int r = 0; r < 4; ++r) sv1[f][r] -= d;
            }
        }

        // P = exp2(sv); packed b64 writes to per-(wave,sub) LDS
        if (has0) {
#pragma unroll
            for (int f = 0; f < 4; ++f) {
                ushort4_t pk;
                pk.x = f2bf(exp2f(sv0[f][0]));
                pk.y = f2bf(exp2f(sv0[f][1]));
                pk.z = f2bf(exp2f(sv0[f][2]));
                pk.w = f2bf(exp2f(sv0[f][3]));
                *(ushort4_t*)&Ps[w][0][lc * 64 + (((4 * f + lr) ^ (lc & 14)) << 2)] = pk;
            }
        }
#pragma unroll
        for (int f = 0; f < 4; ++f) {
            ushort4_t pk;
            pk.x = f2bf(exp2f(sv1[f][0]));
            pk.y = f2bf(exp2f(sv1[f][1]));
            pk.z = f2bf(exp2f(sv1[f][2]));
            pk.w = f2bf(exp2f(sv1[f][3]));
            *(ushort4_t*)&Ps[w][1][lc * 64 + (((4 * f + lr) ^ (lc & 14)) << 2)] = pk;
        }

        // PV + ones-column l; V fragment read once, used by both sub-tiles
        __builtin_amdgcn_s_setprio(1);
#pragma unroll
        for (int kk = 0; kk < 2; ++kk) {
            bf16x8 pf0 = *(const bf16x8*)&Ps[w][0][lc * 64 + (((8 * kk + 2 * lr) ^ (lc & 14)) << 2)];
            bf16x8 pf1 = *(const bf16x8*)&Ps[w][1][lc * 64 + (((8 * kk + 2 * lr) ^ (lc & 14)) << 2)];
            if (has0) l0 = mfma16(pf0, ones, l0);
            l1 = mfma16(pf1, ones, l1);
#pragma unroll
            for (int f = 0; f < 4; ++f) {
                int vrow = 16 * f + lc;
                bf16x8 vfr = *(const bf16x8*)&Vs[cur][vrow * 64 + (((lr + 4 * kk) ^ (vrow & 7)) * 8)];
                if (has0) acc0[f] = mfma16(pf0, vfr, acc0[f]);
                acc1[f] = mfma16(pf1, vfr, acc1[f]);
            }
        }
        __builtin_amdgcn_s_setprio(0);

        asm volatile("s_waitcnt vmcnt(0)" ::: "memory");
        __builtin_amdgcn_s_barrier();
    }

    // normalize + store both sub-tiles
    float inv0[4], inv1[4];
#pragma unroll
    for (int r = 0; r < 4; ++r) { inv0[r] = 1.f / l0[r]; inv1[r] = 1.f / l1[r]; }
#pragma unroll
    for (int f = 0; f < 4; ++f)
#pragma unroll
        for (int r = 0; r < 4; ++r) {
            int t = s * 128 + w * 16 + 4 * lr + r;
            attnb[((size_t)(b * T_ + t)) * 1024 + h * 64 + 16 * f + lc] =
                f2bf(acc0[f][r] * inv0[r]);
            attnb[((size_t)(b * T_ + t + 64)) * 1024 + h * 64 + 16 * f + lc] =
                f2bf(acc1[f][r] * inv1[r]);
        }
}

extern "C" void kernel_launch(void* const* d_in, const int* in_sizes, int n_in,
                              void* d_out, int out_size, void* d_ws, size_t ws_size,
                              hipStream_t stream) {
    const float* hs     = (const float*)d_in[0];
    const float* cosp   = (const float*)d_in[1];
    const float* sinp   = (const float*)d_in[2];
    const float* qkv_w  = (const float*)d_in[3];
    const float* qkv_b  = (const float*)d_in[4];
    const float* proj_w = (const float*)d_in[5];
    const float* proj_b = (const float*)d_in[6];
    float* out = (float*)d_out;

    const int M = B_ * T_;            // 4096
    ushort_t* Xb     = (ushort_t*)d_ws;
    ushort_t* Wqkvb  = Xb + (size_t)M * C_;
    ushort_t* Wprojb = Wqkvb + (size_t)3072 * C_;
    ushort_t* Qr     = Wprojb + (size_t)C_ * C_;
    ushort_t* Kr     = Qr + (size_t)B_ * H_ * T_ * D_;
    ushort_t* Vt     = Kr + (size_t)B_ * H_ * T_ * D_;
    ushort_t* attnb  = Vt + (size_t)B_ * H_ * T_ * D_;

    cvt3_kernel<<<2048, 256, 0, stream>>>(hs, Xb, M * C_,
                                          qkv_w, Wqkvb, 3072 * C_,
                                          proj_w, Wprojb, C_ * C_);

    gemm_qkv_rope<<<768, 256, 0, stream>>>(Xb, Wqkvb, qkv_b, cosp, sinp, Qr, Kr, Vt);

    attn_kernel<<<512, 256, 0, stream>>>(Qr, Kr, Vt, attnb);

    gemm_proj<<<256, 256, 0, stream>>>(attnb, Wprojb, proj_b, out, M, C_, C_, 1024 / 128);
}